// Round 1
// baseline (1791.794 us; speedup 1.0000x reference)
//
#include <hip/hip_runtime.h>

typedef unsigned short u16;
typedef unsigned int u32;
typedef __attribute__((ext_vector_type(8))) short short8;   // 8 x bf16 raw
typedef __attribute__((ext_vector_type(4))) float floatx4;  // MFMA acc

constexpr int Bc = 2, Sc = 2048, Ec = 2048, Hc = 16, Dc = 128;
constexpr int TILE = 128, BK = 32;

// fp32 -> bf16 raw bits, round-to-nearest-even (inputs are finite)
__device__ __forceinline__ u16 f2bf(float f) {
  u32 u = __builtin_bit_cast(u32, f);
  u = (u + 0x7FFFu + ((u >> 16) & 1u)) >> 16;
  return (u16)u;
}

__device__ __forceinline__ short8 pack2(float4 a, float4 b) {
  short8 r;
  r[0] = (short)f2bf(a.x); r[1] = (short)f2bf(a.y);
  r[2] = (short)f2bf(a.z); r[3] = (short)f2bf(a.w);
  r[4] = (short)f2bf(b.x); r[5] = (short)f2bf(b.y);
  r[6] = (short)f2bf(b.z); r[7] = (short)f2bf(b.w);
  return r;
}

// 128x128 tile GEMM core: C[m][n] = sum_k A[m][k] * Bt[n][k]  (both K-major)
// A is fp32 (converted in staging) or bf16-raw per template arg.
// 256 threads = 4 waves in 2x2; each wave: 4x4 MFMA tiles of 16x16x32 bf16.
// LDS: [128][32] bf16 per operand, 8-elem chunks XOR-swizzled by (row&3).
template<bool AF32>
__device__ __forceinline__ void gemm_core(const void* __restrict__ A, int lda,
                                          const u16* __restrict__ Bt, int ldb,
                                          int K, int m0, int n0,
                                          u16* smA, u16* smB,
                                          floatx4 (*acc)[4]) {
  const int t = threadIdx.x;
  const int r = t >> 1;            // staging row 0..127
  const int cg = (t & 1) * 2;      // staging k-chunk pair (chunks of 8 elems)
  const int sw = r & 3;
  const int lane = t & 63;
  const int w = t >> 6;
  const int wr = (w >> 1) * 64, wc = (w & 1) * 64;
  const int l15 = lane & 15, q = lane >> 4;

  for (int k0 = 0; k0 < K; k0 += BK) {
    short8 a0, a1;
    if constexpr (AF32) {
      const float* Af = (const float*)A + (size_t)(m0 + r) * lda + k0 + cg * 8;
      float4 f0 = ((const float4*)Af)[0];
      float4 f1 = ((const float4*)Af)[1];
      float4 f2 = ((const float4*)Af)[2];
      float4 f3 = ((const float4*)Af)[3];
      a0 = pack2(f0, f1);
      a1 = pack2(f2, f3);
    } else {
      const u16* Ab = (const u16*)A + (size_t)(m0 + r) * lda + k0 + cg * 8;
      a0 = *(const short8*)(Ab);
      a1 = *(const short8*)(Ab + 8);
    }
    const u16* Bb = Bt + (size_t)(n0 + r) * ldb + k0 + cg * 8;
    short8 b0 = *(const short8*)(Bb);
    short8 b1 = *(const short8*)(Bb + 8);

    *(short8*)&smA[r * BK + (((cg + 0) ^ sw) << 3)] = a0;
    *(short8*)&smA[r * BK + (((cg + 1) ^ sw) << 3)] = a1;
    *(short8*)&smB[r * BK + (((cg + 0) ^ sw) << 3)] = b0;
    *(short8*)&smB[r * BK + (((cg + 1) ^ sw) << 3)] = b1;
    __syncthreads();

    short8 af[4], bfr[4];
    #pragma unroll
    for (int i = 0; i < 4; i++) {
      int ra = wr + i * 16 + l15;   // A row:  m = lane&15 per MFMA A-layout
      af[i] = *(const short8*)&smA[ra * BK + ((q ^ (ra & 3)) << 3)];
      int rb = wc + i * 16 + l15;   // Bt row: n = lane&15
      bfr[i] = *(const short8*)&smB[rb * BK + ((q ^ (rb & 3)) << 3)];
    }
    #pragma unroll
    for (int mi = 0; mi < 4; mi++)
      #pragma unroll
      for (int ni = 0; ni < 4; ni++)
        acc[mi][ni] = __builtin_amdgcn_mfma_f32_16x16x32_bf16(af[mi], bfr[ni], acc[mi][ni], 0, 0, 0);
    __syncthreads();
  }
}

// ---- weight pre-transpose: WT[n][k] (bf16) from W[k][n] (fp32) ----
__global__ __launch_bounds__(256) void transpose_w(
    const float* __restrict__ Wq, const float* __restrict__ Wk,
    const float* __restrict__ Wv, const float* __restrict__ Wo,
    u16* __restrict__ WT, u16* __restrict__ WoT) {
  __shared__ float tile[32][33];
  const int z = blockIdx.z;
  const float* W = (z == 0) ? Wq : (z == 1) ? Wk : (z == 2) ? Wv : Wo;
  u16* dst = (z < 3) ? (WT + (size_t)z * Ec * Ec) : WoT;
  const int n0 = blockIdx.x * 32, k0 = blockIdx.y * 32;
  const int tx = threadIdx.x, ty = threadIdx.y;
  #pragma unroll
  for (int i = 0; i < 4; i++)
    tile[ty + 8 * i][tx] = W[(size_t)(k0 + ty + 8 * i) * Ec + n0 + tx];
  __syncthreads();
  #pragma unroll
  for (int i = 0; i < 4; i++)
    dst[(size_t)(n0 + ty + 8 * i) * Ec + k0 + tx] = f2bf(tile[tx][ty + 8 * i]);
}

// ---- K1: fused QKV GEMM (N=6144 concat) + bias + RoPE, writes qr/kr bf16 and v transposed ----
__global__ __launch_bounds__(256) void qkv_kernel(
    const float* __restrict__ x, const u16* __restrict__ WT,
    const float* __restrict__ bq, const float* __restrict__ bk, const float* __restrict__ bv,
    const float* __restrict__ sinp, const float* __restrict__ cosp,
    u16* __restrict__ qr, u16* __restrict__ kr, u16* __restrict__ vT) {
  __shared__ u16 smA[TILE * BK], smB[TILE * BK];
  floatx4 acc[4][4] = {};
  const int m0 = blockIdx.y * TILE, n0 = blockIdx.x * TILE;
  gemm_core<true>(x, Ec, WT, Ec, Ec, m0, n0, smA, smB, acc);

  const int t = threadIdx.x, lane = t & 63, w = t >> 6;
  const int wr = (w >> 1) * 64, wc = (w & 1) * 64, l15 = lane & 15, q = lane >> 4;
  #pragma unroll
  for (int mi = 0; mi < 4; mi++) {
    #pragma unroll
    for (int ni = 0; ni < 4; ni++) {
      const int gcol = n0 + wc + ni * 16 + l15;
      const int which = gcol >> 11;          // 0:q 1:k 2:v
      const int e = gcol & 2047, h = e >> 7, d = e & 127;
      const float* bp = (which == 0) ? bq : (which == 1) ? bk : bv;
      const float bias = bp[e];
      #pragma unroll
      for (int rr = 0; rr < 4; rr++) {
        const int grow = m0 + wr + mi * 16 + q * 4 + rr;
        const int b = grow >> 11, s = grow & 2047;
        float val = acc[mi][ni][rr] + bias;
        float pv = __shfl_xor(val, 1);       // partner column (d^1), same row
        if (which < 2) {
          const size_t sc = ((size_t)h * Sc + s) * Dc + d;
          const float c = cosp[sc], sn = sinp[sc];
          const float o = val * c + ((d & 1) ? pv : -pv) * sn;
          u16* dst = which ? kr : qr;
          dst[(((size_t)b * Hc + h) * Sc + s) * Dc + d] = f2bf(o);
        } else {
          vT[(((size_t)b * Hc + h) * Dc + d) * Sc + s] = f2bf(val);
        }
      }
    }
  }
}

// ---- K2a: logits = q k^T / sqrt(D), masked; fp32 into d_out attention region ----
__global__ __launch_bounds__(256) void logits_kernel(
    const u16* __restrict__ qr, const u16* __restrict__ kr,
    const int* __restrict__ maskp, float* __restrict__ attn) {
  __shared__ u16 smA[TILE * BK], smB[TILE * BK];
  floatx4 acc[4][4] = {};
  const int z = blockIdx.z;                  // b*H + h
  const int m0 = blockIdx.y * TILE, n0 = blockIdx.x * TILE;
  const u16* A = qr + (size_t)z * Sc * Dc;
  const u16* Bt = kr + (size_t)z * Sc * Dc;
  gemm_core<false>(A, Dc, Bt, Dc, Dc, m0, n0, smA, smB, acc);

  float* C = attn + (size_t)z * Sc * Sc;
  const int b = z >> 4;
  const float scale = 0.08838834764831845f;  // 1/sqrt(128)
  const int t = threadIdx.x, lane = t & 63, w = t >> 6;
  const int wr = (w >> 1) * 64, wc = (w & 1) * 64, l15 = lane & 15, q = lane >> 4;
  #pragma unroll
  for (int mi = 0; mi < 4; mi++)
    #pragma unroll
    for (int ni = 0; ni < 4; ni++) {
      const int gcol = n0 + wc + ni * 16 + l15;
      #pragma unroll
      for (int rr = 0; rr < 4; rr++) {
        const int grow = m0 + wr + mi * 16 + q * 4 + rr;
        const int mv = maskp[((size_t)b * Sc + grow) * Sc + gcol];
        C[(size_t)grow * Sc + gcol] = mv ? acc[mi][ni][rr] * scale : -9.0e15f;
      }
    }
}

// ---- K3: values = attention @ v  -> valT[b][h][d][i] bf16 ----
__global__ __launch_bounds__(256) void av_kernel(
    const float* __restrict__ attn, const u16* __restrict__ vT,
    u16* __restrict__ valT) {
  __shared__ u16 smA[TILE * BK], smB[TILE * BK];
  floatx4 acc[4][4] = {};
  const int z = blockIdx.z;
  const int m0 = blockIdx.y * TILE, n0 = blockIdx.x * TILE;
  const float* A = attn + (size_t)z * Sc * Sc;
  const u16* Bt = vT + (size_t)z * Dc * Sc;
  gemm_core<true>(A, Sc, Bt, Sc, Sc, m0, n0, smA, smB, acc);

  u16* C = valT + (size_t)z * Dc * Sc;
  const int t = threadIdx.x, lane = t & 63, w = t >> 6;
  const int wr = (w >> 1) * 64, wc = (w & 1) * 64, l15 = lane & 15, q = lane >> 4;
  #pragma unroll
  for (int mi = 0; mi < 4; mi++)
    #pragma unroll
    for (int ni = 0; ni < 4; ni++) {
      const int gcol = n0 + wc + ni * 16 + l15;  // d
      #pragma unroll
      for (int rr = 0; rr < 4; rr++) {
        const int grow = m0 + wr + mi * 16 + q * 4 + rr;  // i
        C[(size_t)gcol * Sc + grow] = f2bf(acc[mi][ni][rr]);
      }
    }
}

// ---- K5: attn_output = attention_weights @ values -> aox[b][s][h*D+d] bf16 ----
__global__ __launch_bounds__(256) void wv_kernel(
    const float* __restrict__ attn, const u16* __restrict__ valT,
    u16* __restrict__ aox) {
  __shared__ u16 smA[TILE * BK], smB[TILE * BK];
  floatx4 acc[4][4] = {};
  const int z = blockIdx.z;
  const int m0 = blockIdx.y * TILE, n0 = blockIdx.x * TILE;
  const float* A = attn + (size_t)z * Sc * Sc;
  const u16* Bt = valT + (size_t)z * Dc * Sc;
  gemm_core<true>(A, Sc, Bt, Sc, Sc, m0, n0, smA, smB, acc);

  const int b = z >> 4, h = z & 15;
  const int t = threadIdx.x, lane = t & 63, w = t >> 6;
  const int wr = (w >> 1) * 64, wc = (w & 1) * 64, l15 = lane & 15, q = lane >> 4;
  #pragma unroll
  for (int mi = 0; mi < 4; mi++)
    #pragma unroll
    for (int ni = 0; ni < 4; ni++) {
      const int gcol = n0 + wc + ni * 16 + l15;  // d
      #pragma unroll
      for (int rr = 0; rr < 4; rr++) {
        const int grow = m0 + wr + mi * 16 + q * 4 + rr;  // s
        aox[((size_t)b * Sc + grow) * Ec + h * Dc + gcol] = f2bf(acc[mi][ni][rr]);
      }
    }
}

// ---- K6: out = aox @ Wo + bo -> fp32 d_out region 0 ----
__global__ __launch_bounds__(256) void out_kernel(
    const u16* __restrict__ aox, const u16* __restrict__ WoT,
    const float* __restrict__ bo, float* __restrict__ outp) {
  __shared__ u16 smA[TILE * BK], smB[TILE * BK];
  floatx4 acc[4][4] = {};
  const int m0 = blockIdx.y * TILE, n0 = blockIdx.x * TILE;
  gemm_core<false>(aox, Ec, WoT, Ec, Ec, m0, n0, smA, smB, acc);

  const int t = threadIdx.x, lane = t & 63, w = t >> 6;
  const int wr = (w >> 1) * 64, wc = (w & 1) * 64, l15 = lane & 15, q = lane >> 4;
  #pragma unroll
  for (int mi = 0; mi < 4; mi++)
    #pragma unroll
    for (int ni = 0; ni < 4; ni++) {
      const int gcol = n0 + wc + ni * 16 + l15;
      const float bias = bo[gcol];
      #pragma unroll
      for (int rr = 0; rr < 4; rr++) {
        const int grow = m0 + wr + mi * 16 + q * 4 + rr;
        outp[(size_t)grow * Ec + gcol] = acc[mi][ni][rr] + bias;
      }
    }
}

// ---- row softmax over 2048 fp32, in place; one block per row ----
__global__ __launch_bounds__(256) void softmax2048(float* __restrict__ buf) {
  float* p = buf + (size_t)blockIdx.x * 2048;
  const int t = threadIdx.x;
  float4 v0 = ((float4*)p)[t * 2];
  float4 v1 = ((float4*)p)[t * 2 + 1];
  float m = fmaxf(fmaxf(fmaxf(v0.x, v0.y), fmaxf(v0.z, v0.w)),
                  fmaxf(fmaxf(v1.x, v1.y), fmaxf(v1.z, v1.w)));
  #pragma unroll
  for (int off = 32; off > 0; off >>= 1) m = fmaxf(m, __shfl_xor(m, off));
  __shared__ float red[4];
  const int w = t >> 6, lane = t & 63;
  if (lane == 0) red[w] = m;
  __syncthreads();
  m = fmaxf(fmaxf(red[0], red[1]), fmaxf(red[2], red[3]));
  v0.x = expf(v0.x - m); v0.y = expf(v0.y - m);
  v0.z = expf(v0.z - m); v0.w = expf(v0.w - m);
  v1.x = expf(v1.x - m); v1.y = expf(v1.y - m);
  v1.z = expf(v1.z - m); v1.w = expf(v1.w - m);
  float s = v0.x + v0.y + v0.z + v0.w + v1.x + v1.y + v1.z + v1.w;
  #pragma unroll
  for (int off = 32; off > 0; off >>= 1) s += __shfl_xor(s, off);
  __syncthreads();
  if (lane == 0) red[w] = s;
  __syncthreads();
  s = red[0] + red[1] + red[2] + red[3];
  const float inv = 1.0f / s;
  v0.x *= inv; v0.y *= inv; v0.z *= inv; v0.w *= inv;
  v1.x *= inv; v1.y *= inv; v1.z *= inv; v1.w *= inv;
  ((float4*)p)[t * 2] = v0;
  ((float4*)p)[t * 2 + 1] = v1;
}

extern "C" void kernel_launch(void* const* d_in, const int* in_sizes, int n_in,
                              void* d_out, int out_size, void* d_ws, size_t ws_size,
                              hipStream_t stream) {
  const float* x     = (const float*)d_in[0];
  const float* sinp  = (const float*)d_in[1];
  const float* cosp  = (const float*)d_in[2];
  const int*   maskp = (const int*)d_in[3];
  const float* Wq    = (const float*)d_in[4];
  const float* bq    = (const float*)d_in[5];
  const float* Wk    = (const float*)d_in[6];
  const float* bk    = (const float*)d_in[7];
  const float* Wv    = (const float*)d_in[8];
  const float* bv    = (const float*)d_in[9];
  const float* Wo    = (const float*)d_in[10];
  const float* bo    = (const float*)d_in[11];

  float* out0 = (float*)d_out;                          // (B,S,E) fp32
  float* attn = out0 + (size_t)Bc * Sc * Ec;            // (B,H,S,S) fp32: attention, then in-place 2nd softmax

  // workspace layout (bf16 raw, elems); total 117,440,512 bytes
  u16* wsp  = (u16*)d_ws;
  u16* WT   = wsp;                                      // [3E][E] Wq^T|Wk^T|Wv^T
  u16* WoT  = wsp + (size_t)3 * Ec * Ec;                // [E][E]
  u16* qr   = WoT + (size_t)Ec * Ec;                    // (B,H,S,D) RoPE'd
  u16* kr   = qr + (size_t)Bc * Hc * Sc * Dc;
  u16* vT   = kr + (size_t)Bc * Hc * Sc * Dc;           // (B,H,D,S)
  u16* valT = vT + (size_t)Bc * Hc * Sc * Dc;           // (B,H,D,S)
  u16* aox  = valT + (size_t)Bc * Hc * Sc * Dc;         // (B,S,E)

  transpose_w<<<dim3(Ec / 32, Ec / 32, 4), dim3(32, 8), 0, stream>>>(Wq, Wk, Wv, Wo, WT, WoT);
  qkv_kernel<<<dim3(48, 32, 1), 256, 0, stream>>>(x, WT, bq, bk, bv, sinp, cosp, qr, kr, vT);
  logits_kernel<<<dim3(16, 16, 32), 256, 0, stream>>>(qr, kr, maskp, attn);
  softmax2048<<<dim3(65536), 256, 0, stream>>>(attn);               // attention = softmax(logits)
  av_kernel<<<dim3(1, 16, 32), 256, 0, stream>>>(attn, vT, valT);   // values = attention @ v
  softmax2048<<<dim3(65536), 256, 0, stream>>>(attn);               // attention_weights (in place, = output 1)
  wv_kernel<<<dim3(1, 16, 32), 256, 0, stream>>>(attn, valT, aox);  // attn_output
  out_kernel<<<dim3(16, 32, 1), 256, 0, stream>>>(aox, WoT, bo, out0);
}

// Round 2
// 1545.456 us; speedup vs baseline: 1.1594x; 1.1594x over previous
//
#include <hip/hip_runtime.h>

typedef unsigned short u16;
typedef unsigned int u32;
typedef __attribute__((ext_vector_type(8))) short short8;   // 8 x bf16 raw
typedef __attribute__((ext_vector_type(4))) float floatx4;  // MFMA acc

constexpr int Bc = 2, Sc = 2048, Ec = 2048, Hc = 16, Dc = 128;
constexpr int TILE = 128, BK = 32;

// fp32 -> bf16 raw bits, round-to-nearest-even
__device__ __forceinline__ u16 f2bf(float f) {
  u32 u = __builtin_bit_cast(u32, f);
  u = (u + 0x7FFFu + ((u >> 16) & 1u)) >> 16;
  return (u16)u;
}

__device__ __forceinline__ short8 pack2(float4 a, float4 b) {
  short8 r;
  r[0] = (short)f2bf(a.x); r[1] = (short)f2bf(a.y);
  r[2] = (short)f2bf(a.z); r[3] = (short)f2bf(a.w);
  r[4] = (short)f2bf(b.x); r[5] = (short)f2bf(b.y);
  r[6] = (short)f2bf(b.z); r[7] = (short)f2bf(b.w);
  return r;
}

// 128x128 tile GEMM core: C[m][n] = sum_k A[m][k] * Bt[n][k], both bf16 K-major.
// 256 threads = 4 waves 2x2; each wave 4x4 MFMA tiles of 16x16x32 bf16.
// LDS [128][32] bf16 per operand, 8-elem chunks XOR-swizzled by (row&3).
__device__ __forceinline__ void gemm_core(const u16* __restrict__ A, int lda,
                                          const u16* __restrict__ Bt, int ldb,
                                          int K, int m0, int n0,
                                          u16* smA, u16* smB,
                                          floatx4 (*acc)[4]) {
  const int t = threadIdx.x;
  const int r = t >> 1;
  const int cg = (t & 1) * 2;
  const int sw = r & 3;
  const int lane = t & 63;
  const int w = t >> 6;
  const int wr = (w >> 1) * 64, wc = (w & 1) * 64;
  const int l15 = lane & 15, q = lane >> 4;

  for (int k0 = 0; k0 < K; k0 += BK) {
    const u16* Ab = A + (size_t)(m0 + r) * lda + k0 + cg * 8;
    short8 a0 = *(const short8*)(Ab);
    short8 a1 = *(const short8*)(Ab + 8);
    const u16* Bb = Bt + (size_t)(n0 + r) * ldb + k0 + cg * 8;
    short8 b0 = *(const short8*)(Bb);
    short8 b1 = *(const short8*)(Bb + 8);

    *(short8*)&smA[r * BK + (((cg + 0) ^ sw) << 3)] = a0;
    *(short8*)&smA[r * BK + (((cg + 1) ^ sw) << 3)] = a1;
    *(short8*)&smB[r * BK + (((cg + 0) ^ sw) << 3)] = b0;
    *(short8*)&smB[r * BK + (((cg + 1) ^ sw) << 3)] = b1;
    __syncthreads();

    short8 af[4], bfr[4];
    #pragma unroll
    for (int i = 0; i < 4; i++) {
      int ra = wr + i * 16 + l15;
      af[i] = *(const short8*)&smA[ra * BK + ((q ^ (ra & 3)) << 3)];
      int rb = wc + i * 16 + l15;
      bfr[i] = *(const short8*)&smB[rb * BK + ((q ^ (rb & 3)) << 3)];
    }
    #pragma unroll
    for (int mi = 0; mi < 4; mi++)
      #pragma unroll
      for (int ni = 0; ni < 4; ni++)
        acc[mi][ni] = __builtin_amdgcn_mfma_f32_16x16x32_bf16(af[mi], bfr[ni], acc[mi][ni], 0, 0, 0);
    __syncthreads();
  }
}

// ---- weight pre-transpose: WT[n][k] (bf16) from W[k][n] (fp32) ----
__global__ __launch_bounds__(256) void transpose_w(
    const float* __restrict__ Wq, const float* __restrict__ Wk,
    const float* __restrict__ Wv, const float* __restrict__ Wo,
    u16* __restrict__ WT, u16* __restrict__ WoT) {
  __shared__ float tile[32][33];
  const int z = blockIdx.z;
  const float* W = (z == 0) ? Wq : (z == 1) ? Wk : (z == 2) ? Wv : Wo;
  u16* dst = (z < 3) ? (WT + (size_t)z * Ec * Ec) : WoT;
  const int n0 = blockIdx.x * 32, k0 = blockIdx.y * 32;
  const int tx = threadIdx.x, ty = threadIdx.y;
  #pragma unroll
  for (int i = 0; i < 4; i++)
    tile[ty + 8 * i][tx] = W[(size_t)(k0 + ty + 8 * i) * Ec + n0 + tx];
  __syncthreads();
  #pragma unroll
  for (int i = 0; i < 4; i++)
    dst[(size_t)(n0 + ty + 8 * i) * Ec + k0 + tx] = f2bf(tile[tx][ty + 8 * i]);
}

// ---- x -> bf16, and zero the s1 accumulator ----
__global__ __launch_bounds__(256) void xcvt_kernel(const float* __restrict__ x,
                                                   u16* __restrict__ xb,
                                                   float* __restrict__ s1) {
  const int i = blockIdx.x * 256 + threadIdx.x;
  const float4 f0 = ((const float4*)x)[(size_t)i * 2];
  const float4 f1 = ((const float4*)x)[(size_t)i * 2 + 1];
  *(short8*)&xb[(size_t)i * 8] = pack2(f0, f1);
  if (blockIdx.x < 64)
    ((float4*)s1)[i] = make_float4(0.f, 0.f, 0.f, 0.f);  // 64*256*4 = 65536 floats
}

// ---- K1: fused QKV GEMM (N=6144 concat, bf16 A) + bias + RoPE ----
__global__ __launch_bounds__(256) void qkv_kernel(
    const u16* __restrict__ xb, const u16* __restrict__ WT,
    const float* __restrict__ bq, const float* __restrict__ bk, const float* __restrict__ bv,
    const float* __restrict__ sinp, const float* __restrict__ cosp,
    u16* __restrict__ qr, u16* __restrict__ kr, u16* __restrict__ vT) {
  __shared__ u16 smA[TILE * BK], smB[TILE * BK];
  floatx4 acc[4][4] = {};
  const int m0 = blockIdx.y * TILE, n0 = blockIdx.x * TILE;
  gemm_core(xb, Ec, WT, Ec, Ec, m0, n0, smA, smB, acc);

  const int t = threadIdx.x, lane = t & 63, w = t >> 6;
  const int wr = (w >> 1) * 64, wc = (w & 1) * 64, l15 = lane & 15, q = lane >> 4;
  #pragma unroll
  for (int mi = 0; mi < 4; mi++) {
    #pragma unroll
    for (int ni = 0; ni < 4; ni++) {
      const int gcol = n0 + wc + ni * 16 + l15;
      const int which = gcol >> 11;          // 0:q 1:k 2:v
      const int e = gcol & 2047, h = e >> 7, d = e & 127;
      const float* bp = (which == 0) ? bq : (which == 1) ? bk : bv;
      const float bias = bp[e];
      #pragma unroll
      for (int rr = 0; rr < 4; rr++) {
        const int grow = m0 + wr + mi * 16 + q * 4 + rr;
        const int b = grow >> 11, s = grow & 2047;
        float val = acc[mi][ni][rr] + bias;
        float pv = __shfl_xor(val, 1);       // partner column (d^1), same row
        if (which < 2) {
          const size_t sc = ((size_t)h * Sc + s) * Dc + d;
          const float c = cosp[sc], sn = sinp[sc];
          const float o = val * c + ((d & 1) ? pv : -pv) * sn;
          u16* dst = which ? kr : qr;
          dst[(((size_t)b * Hc + h) * Sc + s) * Dc + d] = f2bf(o);
        } else {
          vT[(((size_t)b * Hc + h) * Dc + d) * Sc + s] = f2bf(val);
        }
      }
    }
  }
}

// ---- K2: logits = mask(q k^T / sqrt(D)) -> Lo (d_out attn region); s1 += sum exp(L) per row ----
__global__ __launch_bounds__(256) void logits_kernel(
    const u16* __restrict__ qr, const u16* __restrict__ kr,
    const int* __restrict__ maskp, float* __restrict__ Lo, float* __restrict__ s1) {
  __shared__ u16 smA[TILE * BK], smB[TILE * BK];
  floatx4 acc[4][4] = {};
  const int z = blockIdx.z;                  // b*H + h
  const int m0 = blockIdx.y * TILE, n0 = blockIdx.x * TILE;
  gemm_core(qr + (size_t)z * Sc * Dc, Dc, kr + (size_t)z * Sc * Dc, Dc, Dc, m0, n0, smA, smB, acc);

  float* C = Lo + (size_t)z * Sc * Sc;
  const int b = z >> 4;
  const float scale = 0.08838834764831845f;  // 1/sqrt(128)
  const int t = threadIdx.x, lane = t & 63, w = t >> 6;
  const int wr = (w >> 1) * 64, wc = (w & 1) * 64, l15 = lane & 15, q = lane >> 4;
  float rs[4][4];
  #pragma unroll
  for (int mi = 0; mi < 4; mi++)
    #pragma unroll
    for (int rr = 0; rr < 4; rr++) rs[mi][rr] = 0.f;

  #pragma unroll
  for (int mi = 0; mi < 4; mi++)
    #pragma unroll
    for (int ni = 0; ni < 4; ni++) {
      const int gcol = n0 + wc + ni * 16 + l15;
      #pragma unroll
      for (int rr = 0; rr < 4; rr++) {
        const int grow = m0 + wr + mi * 16 + q * 4 + rr;
        const int mv = maskp[((size_t)b * Sc + grow) * Sc + gcol];
        const float val = mv ? acc[mi][ni][rr] * scale : -9.0e15f;
        C[(size_t)grow * Sc + gcol] = val;
        rs[mi][rr] += __expf(val);           // exp(-9e15) -> 0
      }
    }
  // per-row partial: reduce across the 16 lanes (same q) holding the row's cols
  #pragma unroll
  for (int mi = 0; mi < 4; mi++)
    #pragma unroll
    for (int rr = 0; rr < 4; rr++) {
      float xs = rs[mi][rr];
      xs += __shfl_xor(xs, 1);
      xs += __shfl_xor(xs, 2);
      xs += __shfl_xor(xs, 4);
      xs += __shfl_xor(xs, 8);
      if (l15 == 0)
        atomicAdd(&s1[z * Sc + m0 + wr + mi * 16 + q * 4 + rr], xs);
    }
}

// ---- K3: values = softmax1(L) @ v ; also s2[row] = sum exp(a1) ----
__global__ __launch_bounds__(256) void av_kernel(
    const float* __restrict__ L, const u16* __restrict__ vT,
    const float* __restrict__ s1, u16* __restrict__ valT, float* __restrict__ s2) {
  __shared__ u16 smA[TILE * BK], smB[TILE * BK];
  floatx4 acc[4][4] = {};
  const int z = blockIdx.z;
  const int m0 = blockIdx.y * TILE;
  const int t = threadIdx.x;
  const int r = t >> 1, cg = (t & 1) * 2, sw = r & 3;
  const int lane = t & 63, w = t >> 6;
  const int wr = (w >> 1) * 64, wc = (w & 1) * 64;
  const int l15 = lane & 15, q = lane >> 4;

  const float* Arow = L + (size_t)z * Sc * Sc + (size_t)(m0 + r) * Sc + cg * 8;
  const u16*  Brow = vT + (size_t)z * Dc * Sc + (size_t)r * Sc + cg * 8;
  const float inv1 = 1.0f / s1[z * Sc + m0 + r];
  float s2p = 0.0f;

  for (int k0 = 0; k0 < Sc; k0 += BK) {
    float4 f[4];
    #pragma unroll
    for (int j = 0; j < 4; j++) f[j] = ((const float4*)(Arow + k0))[j];
    #pragma unroll
    for (int j = 0; j < 4; j++) {
      float* e = (float*)&f[j];
      #pragma unroll
      for (int u = 0; u < 4; u++) {
        float a1 = __expf(e[u]) * inv1;      // softmax1
        s2p += __expf(a1);
        e[u] = a1;
      }
    }
    short8 a0 = pack2(f[0], f[1]);
    short8 a1v = pack2(f[2], f[3]);
    short8 b0 = *(const short8*)(Brow + k0);
    short8 b1 = *(const short8*)(Brow + k0 + 8);

    *(short8*)&smA[r * BK + (((cg + 0) ^ sw) << 3)] = a0;
    *(short8*)&smA[r * BK + (((cg + 1) ^ sw) << 3)] = a1v;
    *(short8*)&smB[r * BK + (((cg + 0) ^ sw) << 3)] = b0;
    *(short8*)&smB[r * BK + (((cg + 1) ^ sw) << 3)] = b1;
    __syncthreads();

    short8 af[4], bfr[4];
    #pragma unroll
    for (int i = 0; i < 4; i++) {
      int ra = wr + i * 16 + l15;
      af[i] = *(const short8*)&smA[ra * BK + ((q ^ (ra & 3)) << 3)];
      int rb = wc + i * 16 + l15;
      bfr[i] = *(const short8*)&smB[rb * BK + ((q ^ (rb & 3)) << 3)];
    }
    #pragma unroll
    for (int mi = 0; mi < 4; mi++)
      #pragma unroll
      for (int ni = 0; ni < 4; ni++)
        acc[mi][ni] = __builtin_amdgcn_mfma_f32_16x16x32_bf16(af[mi], bfr[ni], acc[mi][ni], 0, 0, 0);
    __syncthreads();
  }

  float o = __shfl_xor(s2p, 1);              // combine the two threads of this row
  if ((t & 1) == 0) s2[z * Sc + m0 + r] = s2p + o;

  u16* C = valT + (size_t)z * Dc * Sc;
  #pragma unroll
  for (int mi = 0; mi < 4; mi++)
    #pragma unroll
    for (int ni = 0; ni < 4; ni++) {
      const int gcol = wc + ni * 16 + l15;   // d
      #pragma unroll
      for (int rr = 0; rr < 4; rr++) {
        const int grow = m0 + wr + mi * 16 + q * 4 + rr;  // i
        C[(size_t)gcol * Sc + grow] = f2bf(acc[mi][ni][rr]);
      }
    }
}

// ---- K4: a2 = softmax2(softmax1(L)); writes a2 fp32 over L (output 1); attn_output = a2 @ values ----
__global__ __launch_bounds__(256) void wv_kernel(
    float* __restrict__ L, const u16* __restrict__ valT,
    const float* __restrict__ s1, const float* __restrict__ s2,
    u16* __restrict__ aox) {
  __shared__ u16 smA[TILE * BK], smB[TILE * BK];
  floatx4 acc[4][4] = {};
  const int z = blockIdx.z;
  const int m0 = blockIdx.y * TILE;
  const int t = threadIdx.x;
  const int r = t >> 1, cg = (t & 1) * 2, sw = r & 3;
  const int lane = t & 63, w = t >> 6;
  const int wr = (w >> 1) * 64, wc = (w & 1) * 64;
  const int l15 = lane & 15, q = lane >> 4;

  float* Arow = L + (size_t)z * Sc * Sc + (size_t)(m0 + r) * Sc + cg * 8;
  const u16* Brow = valT + (size_t)z * Dc * Sc + (size_t)r * Sc + cg * 8;
  const float inv1 = 1.0f / s1[z * Sc + m0 + r];
  const float inv2 = 1.0f / s2[z * Sc + m0 + r];

  for (int k0 = 0; k0 < Sc; k0 += BK) {
    float4 f[4];
    #pragma unroll
    for (int j = 0; j < 4; j++) f[j] = ((const float4*)(Arow + k0))[j];
    #pragma unroll
    for (int j = 0; j < 4; j++) {
      float* e = (float*)&f[j];
      #pragma unroll
      for (int u = 0; u < 4; u++) {
        float a1 = __expf(e[u]) * inv1;      // softmax1
        e[u] = __expf(a1) * inv2;            // softmax2 -> a2
      }
    }
    #pragma unroll
    for (int j = 0; j < 4; j++) ((float4*)(Arow + k0))[j] = f[j];  // attention_weights out
    short8 a0 = pack2(f[0], f[1]);
    short8 a1v = pack2(f[2], f[3]);
    short8 b0 = *(const short8*)(Brow + k0);
    short8 b1 = *(const short8*)(Brow + k0 + 8);

    *(short8*)&smA[r * BK + (((cg + 0) ^ sw) << 3)] = a0;
    *(short8*)&smA[r * BK + (((cg + 1) ^ sw) << 3)] = a1v;
    *(short8*)&smB[r * BK + (((cg + 0) ^ sw) << 3)] = b0;
    *(short8*)&smB[r * BK + (((cg + 1) ^ sw) << 3)] = b1;
    __syncthreads();

    short8 af[4], bfr[4];
    #pragma unroll
    for (int i = 0; i < 4; i++) {
      int ra = wr + i * 16 + l15;
      af[i] = *(const short8*)&smA[ra * BK + ((q ^ (ra & 3)) << 3)];
      int rb = wc + i * 16 + l15;
      bfr[i] = *(const short8*)&smB[rb * BK + ((q ^ (rb & 3)) << 3)];
    }
    #pragma unroll
    for (int mi = 0; mi < 4; mi++)
      #pragma unroll
      for (int ni = 0; ni < 4; ni++)
        acc[mi][ni] = __builtin_amdgcn_mfma_f32_16x16x32_bf16(af[mi], bfr[ni], acc[mi][ni], 0, 0, 0);
    __syncthreads();
  }

  const int b = z >> 4, h = z & 15;
  #pragma unroll
  for (int mi = 0; mi < 4; mi++)
    #pragma unroll
    for (int ni = 0; ni < 4; ni++) {
      const int gcol = wc + ni * 16 + l15;   // d
      #pragma unroll
      for (int rr = 0; rr < 4; rr++) {
        const int grow = m0 + wr + mi * 16 + q * 4 + rr;  // s
        aox[((size_t)b * Sc + grow) * Ec + h * Dc + gcol] = f2bf(acc[mi][ni][rr]);
      }
    }
}

// ---- K5: out = aox @ Wo + bo -> fp32 d_out region 0 ----
__global__ __launch_bounds__(256) void out_kernel(
    const u16* __restrict__ aox, const u16* __restrict__ WoT,
    const float* __restrict__ bo, float* __restrict__ outp) {
  __shared__ u16 smA[TILE * BK], smB[TILE * BK];
  floatx4 acc[4][4] = {};
  const int m0 = blockIdx.y * TILE, n0 = blockIdx.x * TILE;
  gemm_core(aox, Ec, WoT, Ec, Ec, m0, n0, smA, smB, acc);

  const int t = threadIdx.x, lane = t & 63, w = t >> 6;
  const int wr = (w >> 1) * 64, wc = (w & 1) * 64, l15 = lane & 15, q = lane >> 4;
  #pragma unroll
  for (int mi = 0; mi < 4; mi++)
    #pragma unroll
    for (int ni = 0; ni < 4; ni++) {
      const int gcol = n0 + wc + ni * 16 + l15;
      const float bias = bo[gcol];
      #pragma unroll
      for (int rr = 0; rr < 4; rr++) {
        const int grow = m0 + wr + mi * 16 + q * 4 + rr;
        outp[(size_t)grow * Ec + gcol] = acc[mi][ni][rr] + bias;
      }
    }
}

extern "C" void kernel_launch(void* const* d_in, const int* in_sizes, int n_in,
                              void* d_out, int out_size, void* d_ws, size_t ws_size,
                              hipStream_t stream) {
  const float* x     = (const float*)d_in[0];
  const float* sinp  = (const float*)d_in[1];
  const float* cosp  = (const float*)d_in[2];
  const int*   maskp = (const int*)d_in[3];
  const float* Wq    = (const float*)d_in[4];
  const float* bq    = (const float*)d_in[5];
  const float* Wk    = (const float*)d_in[6];
  const float* bk    = (const float*)d_in[7];
  const float* Wv    = (const float*)d_in[8];
  const float* bv    = (const float*)d_in[9];
  const float* Wo    = (const float*)d_in[10];
  const float* bo    = (const float*)d_in[11];

  float* out0  = (float*)d_out;                         // (B,S,E) fp32
  float* attnL = out0 + (size_t)Bc * Sc * Ec;           // (B,H,S,S): logits, then attention_weights in place

  // workspace (u16 elems unless noted)
  u16* wsp  = (u16*)d_ws;
  u16* WT   = wsp;                                      // [3E][E]
  u16* WoT  = WT + (size_t)3 * Ec * Ec;                 // [E][E]
  u16* xb   = WoT + (size_t)Ec * Ec;                    // (B,S,E) bf16
  u16* qr   = xb + (size_t)Bc * Sc * Ec;                // (B,H,S,D)
  u16* kr   = qr + (size_t)Bc * Hc * Sc * Dc;
  u16* vT   = kr + (size_t)Bc * Hc * Sc * Dc;           // (B,H,D,S)
  u16* valT = vT + (size_t)Bc * Hc * Sc * Dc;           // (B,H,D,S)
  u16* aox  = valT + (size_t)Bc * Hc * Sc * Dc;         // (B,S,E)
  float* s1 = (float*)(aox + (size_t)Bc * Sc * Ec);     // (B,H,S)
  float* s2 = s1 + (size_t)Bc * Hc * Sc;                // (B,H,S)

  transpose_w<<<dim3(64, 64, 4), dim3(32, 8), 0, stream>>>(Wq, Wk, Wv, Wo, WT, WoT);
  xcvt_kernel<<<dim3(4096), 256, 0, stream>>>(x, xb, s1);
  qkv_kernel<<<dim3(48, 32), 256, 0, stream>>>(xb, WT, bq, bk, bv, sinp, cosp, qr, kr, vT);
  logits_kernel<<<dim3(16, 16, 32), 256, 0, stream>>>(qr, kr, maskp, attnL, s1);
  av_kernel<<<dim3(1, 16, 32), 256, 0, stream>>>(attnL, vT, s1, valT, s2);
  wv_kernel<<<dim3(1, 16, 32), 256, 0, stream>>>(attnL, valT, s1, s2, aox);
  out_kernel<<<dim3(16, 32), 256, 0, stream>>>(aox, WoT, bo, out0);
}